// Round 4
// baseline (189.361 us; speedup 1.0000x reference)
//
#include <hip/hip_runtime.h>

// Fused separable 11x11 gaussian + SSIM/charb/MSE, wave-streaming form.
// R9: R8 body (h-ring, literal ring indices, next-row register prefetch,
// launch_bounds(256,2) => VGPR 80, zero spill) at STRH=32.
// R8 (STRH=64) capped itself at 3072 wave-tiles = 12 waves/CU; VALUBusy
// 54% -> 46% of issue slots idle with only 3 waves/SIMD to hide LDS and
// residual global latency. STRH=32 gives 6144 wave-tiles = 24 waves/CU
// (VGPR 80 -> 6 waves/SIMD; LDS 5120B x 6 blocks = 30KB). VALU work
// grows 13.6% (42 steps/32 rows vs 74/64) but issue occupancy doubles:
// predicted 62-70us. R5 (same grid, 99us) differed in the two stall
// sources now removed: no prefetch + per-step 44-FMA acc-ring.
// LDS read/write pointers hoisted per parity -> taps are offset-folded
// ds_read_b64 with zero per-step address VALU.
//
// Per step: commit prefetched row to wave-private dbuf LDS row (parity
// i&1, wave_barrier only) -> issue NEXT row's global loads (consumed at
// the next step's commit; vmcnt hides under taps+finalize) -> 11
// ds_read_b64 horizontal taps {x, y, x^2+y^2, x*y} -> h-ring slot u ->
// vertical 44-FMA finalize once per output row.
// Ring algebra: step i (u=i%11) -> h slot u; finalize at i>=10 emits row
// o=row0+i-10 with weight GW[(u-s) mod 11] (GW symmetric); center diff
// dring[u] read 5 steps later at (u+6)%11. Out-of-range rows give h=0.

#define IMG    512
#define RAD    5
#define KW     11
#define STRH   32
#define NSTEP  (STRH + 2 * RAD)   // 42
#define ROWE   74                 // halo row entries (64 + 2*5)
#define PLANE  (IMG * IMG)

#define C1F  1e-4f
#define C2F  9e-4f
#define EPS2 1e-12f

#define W0 0.00102838f
#define W1 0.00759876f
#define W2 0.03600076f
#define W3 0.10936067f
#define W4 0.21300537f
#define W5 0.26601297f

__global__ __launch_bounds__(256, 2)
void CombinedLossSSIMCharbMSE_81372450390186_kernel(
    const float* __restrict__ pred,
    const float* __restrict__ target,
    float* __restrict__ out)
{
    const float GW[KW] = {W0, W1, W2, W3, W4, W5, W4, W3, W2, W1, W0};

    __shared__ float2 rb[8 * ROWE];   // 4 waves x 2 row buffers, 4736 B

    const int lane = threadIdx.x & 63;
    const int wav  = threadIdx.x >> 6;
    const int wid  = (blockIdx.x << 2) | wav;   // global wave id
    const int plane = wid >> 7;                 // 128 waves per plane
    const int tile  = (wid >> 3) & 15;          // 16 row-tiles of 32
    const int strip = wid & 7;                  // 8 col-strips of 64
    const int col0 = strip << 6;
    const int row0 = tile << 5;
    const int pbase = plane * PLANE;

    // Column geometry (constant across rows). Entry e <-> col col0-5+e.
    const int  cA  = col0 - RAD + lane;         // entries 0..63
    const bool okA = (cA >= 0) & (cA < IMG);
    const int  cAc = min(max(cA, 0), IMG - 1);
    const int  cB  = col0 + 59 + lane;          // entries 64..73 (lanes 0..9)
    const bool okB = cB < IMG;
    const int  cBc = min(cB, IMG - 1);
    const bool doB = lane < 10;

    // Hoisted LDS pointers (per parity): zero per-step address VALU.
    float2* const w0 = &rb[((wav << 1) | 0) * ROWE] + lane;
    float2* const w1 = &rb[((wav << 1) | 1) * ROWE] + lane;

    float hrx[KW], hry[KW], hrs[KW], hrp[KW], dring[KW];
#pragma unroll
    for (int s = 0; s < KW; ++s) {
        hrx[s] = 0.f; hry[s] = 0.f; hrs[s] = 0.f; hrp[s] = 0.f; dring[s] = 0.f;
    }

    float pAr = 0.f, tAr = 0.f, pBr = 0.f, tBr = 0.f;   // prefetch regs

#define LOAD_ROW(rr) do {                                                   \
        const int _base = pbase + (rr) * IMG;                               \
        pAr = pred[_base + cAc];   pAr = okA ? pAr : 0.f;                   \
        tAr = target[_base + cAc]; tAr = okA ? tAr : 0.f;                   \
        if (doB) {                                                          \
            pBr = pred[_base + cBc];   pBr = okB ? pBr : 0.f;               \
            tBr = target[_base + cBc]; tBr = okB ? tBr : 0.f;               \
        }                                                                   \
    } while (0)

#define COMMIT(par) do {                                                    \
        float2* _wp = (par) ? w1 : w0;                                      \
        _wp[0] = make_float2(pAr, tAr);                                     \
        if (doB) _wp[64] = make_float2(pBr, tBr);                           \
        __builtin_amdgcn_wave_barrier();  /* keep write->read order */      \
    } while (0)

#define TAPS(uu, par) do {                                                  \
        const float2* _rp = (par) ? w1 : w0;                                \
        float _hx = 0.f, _hy = 0.f, _hs = 0.f, _hp = 0.f;                   \
        float2 _c5 = make_float2(0.f, 0.f);                                 \
        _Pragma("unroll")                                                   \
        for (int _d = 0; _d < KW; ++_d) {                                   \
            const float2 _t = _rp[_d];                                      \
            if (_d == RAD) _c5 = _t;                                        \
            const float _w = GW[_d];                                        \
            _hx = fmaf(_w, _t.x, _hx);                                      \
            _hy = fmaf(_w, _t.y, _hy);                                      \
            _hs = fmaf(_w, fmaf(_t.x, _t.x, _t.y * _t.y), _hs);             \
            _hp = fmaf(_w, _t.x * _t.y, _hp);                               \
        }                                                                   \
        hrx[uu] = _hx; hry[uu] = _hy; hrs[uu] = _hs; hrp[uu] = _hp;         \
        dring[uu] = _c5.x - _c5.y;     /* center diff, used at step i+5 */  \
    } while (0)

#define ZERO_H(uu) do {                                                     \
        hrx[uu] = 0.f; hry[uu] = 0.f; hrs[uu] = 0.f; hrp[uu] = 0.f;         \
    } while (0)

#define FINALIZE(uu, oo) do {                                               \
        float _vx = 0.f, _vy = 0.f, _vs = 0.f, _vp = 0.f;                   \
        _Pragma("unroll")                                                   \
        for (int _s = 0; _s < KW; ++_s) {                                   \
            const float _w = GW[((uu) - _s + KW) % KW];                     \
            _vx = fmaf(_w, hrx[_s], _vx);                                   \
            _vy = fmaf(_w, hry[_s], _vy);                                   \
            _vs = fmaf(_w, hrs[_s], _vs);                                   \
            _vp = fmaf(_w, hrp[_s], _vp);                                   \
        }                                                                   \
        const float _mxy = _vx * _vy;                                       \
        const float _mu2 = fmaf(_vx, _vx, _vy * _vy);                       \
        const float _A1 = fmaf(2.f, _mxy, C1F);                             \
        const float _A2 = fmaf(2.f, _vp - _mxy, C2F);                       \
        const float _B1 = _mu2 + C1F;                                       \
        const float _B2 = (_vs - _mu2) + C2F;                               \
        const float _ssim = (_A1 * _A2) * __builtin_amdgcn_rcpf(_B1 * _B2); \
        const float _dd = dring[((uu) + 6) % KW];  /* written step i-5 */   \
        const float _ch = __builtin_amdgcn_sqrtf(fmaf(_dd, _dd, EPS2));     \
        out[pbase + (oo) * IMG + col0 + lane] =                             \
            fmaf(0.3f, _ch, fmaf(2.0f, _dd * _dd, 0.6f * (1.f - _ssim)));   \
    } while (0)

    // ---- prologue: steps i = 0..10 (u = i), row r = row0-5+i -------------
    if (row0 > 0) LOAD_ROW(row0 - RAD);   // prefetch for step 0

#define STEP_PRO(uu) do {                                                   \
        const bool _inr = (row0 - RAD + (uu)) >= 0;      /* wave-uniform */ \
        if (_inr) COMMIT((uu) & 1);                                         \
        if ((row0 - RAD + (uu) + 1) >= 0) LOAD_ROW(row0 - RAD + (uu) + 1);  \
        if (_inr) TAPS(uu, (uu) & 1); else ZERO_H(uu);                      \
    } while (0)

    STEP_PRO(0); STEP_PRO(1); STEP_PRO(2); STEP_PRO(3); STEP_PRO(4);
    STEP_PRO(5); STEP_PRO(6); STEP_PRO(7); STEP_PRO(8); STEP_PRO(9);
    STEP_PRO(10);
    FINALIZE(10, row0);                    // first output row at i = 10

    // ---- interior: k = 1..2, steps i = 11..32 — branch-free --------------
    for (int k = 1; k <= 2; ++k) {
        const int rnext = row0 - RAD + k * KW + 1;  // prefetch row at +uu
        const int obase = row0 + k * KW - 10;       // output row at +uu
        const int kp = k & 1;                       // i parity = kp^(uu&1)
#define STEP_FULL(uu) do {                                                  \
        COMMIT(kp ^ ((uu) & 1));                                            \
        LOAD_ROW(rnext + (uu));                                             \
        TAPS(uu, kp ^ ((uu) & 1));                                          \
        FINALIZE(uu, obase + (uu));                                         \
    } while (0)
        STEP_FULL(0); STEP_FULL(1); STEP_FULL(2); STEP_FULL(3);
        STEP_FULL(4); STEP_FULL(5); STEP_FULL(6); STEP_FULL(7);
        STEP_FULL(8); STEP_FULL(9); STEP_FULL(10);
#undef STEP_FULL
    }

    // ---- epilogue: steps i = 33..41 (u = 0..8), row r = row0+28+u --------
    // parity of i = 33+u is (u+1)&1.
#define STEP_EPI(uu) do {                                                   \
        const bool _inr = (row0 + 28 + (uu)) < IMG;      /* wave-uniform */ \
        if (_inr) COMMIT(((uu) + 1) & 1);                                   \
        if (((uu) < 8) && (row0 + 29 + (uu)) < IMG)                         \
            LOAD_ROW(row0 + 29 + (uu));                                     \
        if (_inr) TAPS(uu, ((uu) + 1) & 1); else ZERO_H(uu);                \
        FINALIZE(uu, row0 + 23 + (uu));                                     \
    } while (0)

    STEP_EPI(0); STEP_EPI(1); STEP_EPI(2); STEP_EPI(3);
    STEP_EPI(4); STEP_EPI(5); STEP_EPI(6); STEP_EPI(7); STEP_EPI(8);
#undef STEP_EPI
#undef STEP_PRO
#undef FINALIZE
#undef ZERO_H
#undef TAPS
#undef COMMIT
#undef LOAD_ROW
}

extern "C" void kernel_launch(void* const* d_in, const int* in_sizes, int n_in,
                              void* d_out, int out_size, void* d_ws, size_t ws_size,
                              hipStream_t stream) {
    const float* pred = (const float*)d_in[0];
    const float* target = (const float*)d_in[1];
    float* out = (float*)d_out;
    const int planes = in_sizes[0] / PLANE;     // 48

    // 128 waves per plane (8 strips x 16 tiles of 32 rows), 4 waves/block.
    dim3 grid(planes * 32);                     // 1536 blocks = 6 per CU
    CombinedLossSSIMCharbMSE_81372450390186_kernel<<<grid, dim3(256), 0, stream>>>(
        pred, target, out);
}

// Round 5
// 164.663 us; speedup vs baseline: 1.1500x; 1.1500x over previous
//
#include <hip/hip_runtime.h>

// Fused separable 11x11 gaussian + SSIM/charb/MSE, wave-streaming form.
// R10: R8 geometry (STRH=64, 768 blocks = 3 blocks/CU, launch_bounds(256,2))
// + PREFETCH DEPTH 2. R9 diagnosis: per-step VALU issue is ~530cy in all
// variants, but every step carries a 440-780cy unhidden vmcnt stall --
// depth-1 prefetch gives only one step of in-flight time and the waves
// convoy (same phase), so extra waves don't cover it. Depth 2: two
// register sets ping-ponged by step parity; step i COMMITs set (i&1)
// (loaded at step i-2) and issues row r+2 into that set. The compiler's
// wait at COMMIT becomes a counted vmcnt (newest 4 loads outstanding),
// doubling the latency budget to ~1060cy/wave.
// Register sets need LITERAL parity (token pasting), so the schedule is
// 11 prologue + 11 unrolled + 2 x (22-step loop body) + 8 epilogue; ring
// index u = i%11 and parity i&1 are compile-time in every body (22 is a
// multiple of 2 and is 0 mod 11, so the loop is phase-invariant).
// Single LDS row buffer per wave (592B): intra-wave DS ops complete in
// order (lgkmcnt is in-order), so next step's ds_write cannot bypass this
// step's ds_reads -- the double buffer was unnecessary. Boundary masking
// (okA/okB) moved from load-site to commit-site so loads have no
// immediate consumer and can stay in flight the full 2 steps.
// Ring algebra: step i (u=i%11) -> h slot u; finalize at i>=10 emits
// output row o = r-5 with weight GW[(u-s) mod 11] (GW symmetric); center
// diff dring[u] read 5 steps later at (u+6)%11. Out-of-range rows: h=0.

#define IMG    512
#define RAD    5
#define KW     11
#define STRH   64
#define ROWE   74                 // halo row entries (64 + 2*5)
#define PLANE  (IMG * IMG)

#define C1F  1e-4f
#define C2F  9e-4f
#define EPS2 1e-12f

#define W0 0.00102838f
#define W1 0.00759876f
#define W2 0.03600076f
#define W3 0.10936067f
#define W4 0.21300537f
#define W5 0.26601297f

__global__ __launch_bounds__(256, 2)
void CombinedLossSSIMCharbMSE_81372450390186_kernel(
    const float* __restrict__ pred,
    const float* __restrict__ target,
    float* __restrict__ out)
{
    const float GW[KW] = {W0, W1, W2, W3, W4, W5, W4, W3, W2, W1, W0};

    __shared__ float2 rb[4 * ROWE];   // 4 waves x 1 row buffer, 2368 B

    const int lane = threadIdx.x & 63;
    const int wav  = threadIdx.x >> 6;
    const int wid  = (blockIdx.x << 2) | wav;   // global wave id
    const int plane = wid >> 6;                 // 64 waves per plane
    const int tile  = (wid >> 3) & 7;           // 8 row-tiles of 64
    const int strip = wid & 7;                  // 8 col-strips of 64
    const int col0 = strip << 6;
    const int row0 = tile << 6;
    const int pbase = plane * PLANE;

    // Column geometry (constant across rows). Entry e <-> col col0-5+e.
    const int  cA  = col0 - RAD + lane;         // entries 0..63
    const bool okA = (cA >= 0) & (cA < IMG);
    const int  cAc = min(max(cA, 0), IMG - 1);
    const int  cB  = col0 + 59 + lane;          // entries 64..73 (lanes 0..9)
    const bool okB = cB < IMG;
    const int  cBc = min(cB, IMG - 1);
    const bool doB = lane < 10;

    const int wb = wav * ROWE;                  // LDS row base (single buf)

    float hrx[KW], hry[KW], hrs[KW], hrp[KW], dring[KW];
#pragma unroll
    for (int s = 0; s < KW; ++s) {
        hrx[s] = 0.f; hry[s] = 0.f; hrs[s] = 0.f; hrp[s] = 0.f; dring[s] = 0.f;
    }

    // Two prefetch register sets (depth 2), ping-ponged by step parity.
    float pA0 = 0.f, tA0 = 0.f, pB0 = 0.f, tB0 = 0.f;
    float pA1 = 0.f, tA1 = 0.f, pB1 = 0.f, tB1 = 0.f;

#define LOADR(ss, rr) do {                                                  \
        const int _b = pbase + (rr) * IMG;                                  \
        pA##ss = pred[_b + cAc];                                            \
        tA##ss = target[_b + cAc];                                          \
        if (doB) {                                                          \
            pB##ss = pred[_b + cBc];                                        \
            tB##ss = target[_b + cBc];                                      \
        }                                                                   \
    } while (0)

#define COMMITR(ss) do {                                                    \
        rb[wb + lane] =                                                     \
            make_float2(okA ? pA##ss : 0.f, okA ? tA##ss : 0.f);            \
        if (doB) rb[wb + 64 + lane] =                                       \
            make_float2(okB ? pB##ss : 0.f, okB ? tB##ss : 0.f);            \
        __builtin_amdgcn_wave_barrier();  /* keep write->read order */      \
    } while (0)

#define TAPS(uu) do {                                                       \
        float _hx = 0.f, _hy = 0.f, _hs = 0.f, _hp = 0.f;                   \
        float2 _c5 = make_float2(0.f, 0.f);                                 \
        _Pragma("unroll")                                                   \
        for (int _d = 0; _d < KW; ++_d) {                                   \
            const float2 _t = rb[wb + lane + _d];                           \
            if (_d == RAD) _c5 = _t;                                        \
            const float _w = GW[_d];                                        \
            _hx = fmaf(_w, _t.x, _hx);                                      \
            _hy = fmaf(_w, _t.y, _hy);                                      \
            _hs = fmaf(_w, fmaf(_t.x, _t.x, _t.y * _t.y), _hs);             \
            _hp = fmaf(_w, _t.x * _t.y, _hp);                               \
        }                                                                   \
        hrx[uu] = _hx; hry[uu] = _hy; hrs[uu] = _hs; hrp[uu] = _hp;         \
        dring[uu] = _c5.x - _c5.y;     /* center diff, used at step i+5 */  \
    } while (0)

#define ZERO_H(uu) do {                                                     \
        hrx[uu] = 0.f; hry[uu] = 0.f; hrs[uu] = 0.f; hrp[uu] = 0.f;         \
    } while (0)

#define FINALIZE(uu, oo) do {                                               \
        float _vx = 0.f, _vy = 0.f, _vs = 0.f, _vp = 0.f;                   \
        _Pragma("unroll")                                                   \
        for (int _s = 0; _s < KW; ++_s) {                                   \
            const float _w = GW[((uu) - _s + KW) % KW];                     \
            _vx = fmaf(_w, hrx[_s], _vx);                                   \
            _vy = fmaf(_w, hry[_s], _vy);                                   \
            _vs = fmaf(_w, hrs[_s], _vs);                                   \
            _vp = fmaf(_w, hrp[_s], _vp);                                   \
        }                                                                   \
        const float _mxy = _vx * _vy;                                       \
        const float _mu2 = fmaf(_vx, _vx, _vy * _vy);                       \
        const float _A1 = fmaf(2.f, _mxy, C1F);                             \
        const float _A2 = fmaf(2.f, _vp - _mxy, C2F);                       \
        const float _B1 = _mu2 + C1F;                                       \
        const float _B2 = (_vs - _mu2) + C2F;                               \
        const float _ssim = (_A1 * _A2) * __builtin_amdgcn_rcpf(_B1 * _B2); \
        const float _dd = dring[((uu) + 6) % KW];  /* written step i-5 */   \
        const float _ch = __builtin_amdgcn_sqrtf(fmaf(_dd, _dd, EPS2));     \
        out[pbase + (oo) * IMG + col0 + lane] =                             \
            fmaf(0.3f, _ch, fmaf(2.0f, _dd * _dd, 0.6f * (1.f - _ssim)));   \
    } while (0)

    // ---- init prefetch: rows row0-5 (set0), row0-4 (set1) ----------------
    if (row0 > 0) { LOADR(0, row0 - 5); LOADR(1, row0 - 4); }

    // ---- prologue: steps i = 0..10 (u = i, set = i&1), r = row0-5+i ------
#define STEP_PRO(uu, ss) do {                                               \
        const bool _inr = (row0 - RAD + (uu)) >= 0;      /* wave-uniform */ \
        if (_inr) COMMITR(ss);                                              \
        if ((row0 - 3 + (uu)) >= 0) LOADR(ss, row0 - 3 + (uu));             \
        if (_inr) TAPS(uu); else ZERO_H(uu);                                \
    } while (0)

    STEP_PRO(0, 0); STEP_PRO(1, 1); STEP_PRO(2, 0); STEP_PRO(3, 1);
    STEP_PRO(4, 0); STEP_PRO(5, 1); STEP_PRO(6, 0); STEP_PRO(7, 1);
    STEP_PRO(8, 0); STEP_PRO(9, 1); STEP_PRO(10, 0);
    FINALIZE(10, row0);                    // first output row at i = 10

    // ---- block A: steps i = 11..21 (u = m, set = (m+1)&1), r = row0+6+m --
#define STEP_A(m, ss) do {                                                  \
        COMMITR(ss);                                                        \
        LOADR(ss, row0 + 8 + (m));                                          \
        TAPS(m);                                                            \
        FINALIZE(m, row0 + 1 + (m));                                        \
    } while (0)

    STEP_A(0, 1); STEP_A(1, 0); STEP_A(2, 1); STEP_A(3, 0); STEP_A(4, 1);
    STEP_A(5, 0); STEP_A(6, 1); STEP_A(7, 0); STEP_A(8, 1); STEP_A(9, 0);
    STEP_A(10, 1);
#undef STEP_A

    // ---- interior loop: j = 0,1; 22 steps each (i = 22+22j+t) ------------
    // u = t%11, set = t&1 (both literal); r = rbase+t; o = r-5.
    for (int j = 0; j < 2; ++j) {
        const int rbase = row0 + 17 + 22 * j;
#define STEP_I(t, uu, ss) do {                                              \
        COMMITR(ss);                                                        \
        LOADR(ss, rbase + (t) + 2);                                         \
        TAPS(uu);                                                           \
        FINALIZE(uu, rbase + (t) - 5);                                      \
    } while (0)
        STEP_I(0, 0, 0);   STEP_I(1, 1, 1);   STEP_I(2, 2, 0);
        STEP_I(3, 3, 1);   STEP_I(4, 4, 0);   STEP_I(5, 5, 1);
        STEP_I(6, 6, 0);   STEP_I(7, 7, 1);   STEP_I(8, 8, 0);
        STEP_I(9, 9, 1);   STEP_I(10, 10, 0); STEP_I(11, 0, 1);
        STEP_I(12, 1, 0);  STEP_I(13, 2, 1);  STEP_I(14, 3, 0);
        STEP_I(15, 4, 1);  STEP_I(16, 5, 0);  STEP_I(17, 6, 1);
        STEP_I(18, 7, 0);  STEP_I(19, 8, 1);  STEP_I(20, 9, 0);
        STEP_I(21, 10, 1);
#undef STEP_I
    }

    // ---- epilogue: steps i = 66..73 (u = m, set = m&1), r = row0+61+m ----
#define STEP_E(m, ss) do {                                                  \
        const bool _inr = (row0 + 61 + (m)) < IMG;       /* wave-uniform */ \
        if (_inr) COMMITR(ss);                                              \
        if (((m) < 6) && (row0 + 63 + (m)) < IMG)                           \
            LOADR(ss, row0 + 63 + (m));                                     \
        if (_inr) TAPS(m); else ZERO_H(m);                                  \
        FINALIZE(m, row0 + 56 + (m));                                       \
    } while (0)

    STEP_E(0, 0); STEP_E(1, 1); STEP_E(2, 0); STEP_E(3, 1);
    STEP_E(4, 0); STEP_E(5, 1); STEP_E(6, 0); STEP_E(7, 1);
#undef STEP_E
#undef STEP_PRO
#undef FINALIZE
#undef ZERO_H
#undef TAPS
#undef COMMITR
#undef LOADR
}

extern "C" void kernel_launch(void* const* d_in, const int* in_sizes, int n_in,
                              void* d_out, int out_size, void* d_ws, size_t ws_size,
                              hipStream_t stream) {
    const float* pred = (const float*)d_in[0];
    const float* target = (const float*)d_in[1];
    float* out = (float*)d_out;
    const int planes = in_sizes[0] / PLANE;     // 48

    // 64 waves per plane (8 strips x 8 tiles of 64 rows), 4 waves/block.
    dim3 grid(planes * 16);                     // 768 blocks = 3 per CU
    CombinedLossSSIMCharbMSE_81372450390186_kernel<<<grid, dim3(256), 0, stream>>>(
        pred, target, out);
}